// Round 2
// baseline (3235.052 us; speedup 1.0000x reference)
//
#include <hip/hip_runtime.h>
#include <hip/hip_bf16.h>
#include <math.h>

#define HW   65536   // 256*256
#define WID  256
#define NB   8
#define NT   6
#define NC   48      // nt*nb combined channels
#define DIM  64
#define EE   128

__device__ __forceinline__ float gelu_exact(float v) {
    return 0.5f * v * (1.0f + erff(v * 0.70710678118654752f));
}

// ---------------- Kernel A: fold prompt into conv weights ----------------
// Wf[(tk*9+rs)*128 + o] = sum_e conv_w[o][e][rs] * prompt[tk][e]
__global__ __launch_bounds__(128) void fold_weights_kernel(
    const float* __restrict__ conv_w,   // [128][128][3][3]
    const float* __restrict__ prompt,   // [6][8][128]
    float* __restrict__ Wf)             // [48*9][128]
{
    int tk = blockIdx.x / 9;
    int rs = blockIdx.x % 9;
    int o  = threadIdx.x;
    const float* pw = conv_w + (size_t)o * EE * 9 + rs;
    const float* pp = prompt + tk * EE;
    float acc = 0.f;
    #pragma unroll 4
    for (int e = 0; e < EE; ++e)
        acc += pw[(size_t)e * 9] * pp[e];
    Wf[(size_t)(tk * 9 + rs) * EE + o] = acc;
}

// ---------------- Kernel B: per-pixel routing -> c[b][48][h][w] (bf16) ----------------
__global__ __launch_bounds__(256) void routing_kernel(
    const float* __restrict__ x,      // [8][64][256][256]
    const float* __restrict__ flux,   // [8][128][256][256]
    const float* __restrict__ b1w, const float* __restrict__ b1b,
    const float* __restrict__ b2w, const float* __restrict__ b2b,
    const float* __restrict__ t1w, const float* __restrict__ t1b,
    const float* __restrict__ t2w, const float* __restrict__ t2b,
    __hip_bfloat16* __restrict__ c)   // [8][48][256][256]
{
    __shared__ float s_b1w[DIM * 8];   // [ci][j] transposed
    __shared__ float s_t1w[EE * 8];    // [ci][j] transposed, j<6 padded with 0
    __shared__ float s_b2w[64];
    __shared__ float s_t2w[36];
    __shared__ float s_b1b[8], s_b2b[8], s_t1b[8], s_t2b[8];

    int tid = threadIdx.x;
    for (int i = tid; i < DIM * 8; i += 256) {
        int ci = i >> 3, j = i & 7;
        s_b1w[i] = b1w[j * DIM + ci];
    }
    for (int i = tid; i < EE * 8; i += 256) {
        int ci = i >> 3, j = i & 7;
        s_t1w[i] = (j < NT) ? t1w[j * EE + ci] : 0.f;
    }
    if (tid < 64) s_b2w[tid] = b2w[tid];
    if (tid < 36) s_t2w[tid] = t2w[tid];
    if (tid < 8) {
        s_b1b[tid] = b1b[tid];
        s_b2b[tid] = b2b[tid];
        s_t1b[tid] = (tid < NT) ? t1b[tid] : 0.f;
        s_t2b[tid] = (tid < NT) ? t2b[tid] : 0.f;
    }
    __syncthreads();

    int pid = blockIdx.x * 256 + tid;     // 0 .. 524287
    int b  = pid >> 16;
    int yx = pid & (HW - 1);

    // ---- MLP1 on x (64 -> 8) ----
    float a[8];
    #pragma unroll
    for (int j = 0; j < 8; ++j) a[j] = s_b1b[j];
    const float* xp = x + (size_t)b * DIM * HW + yx;
    #pragma unroll 8
    for (int ci = 0; ci < DIM; ++ci) {
        float v = xp[(size_t)ci * HW];
        float4 wa = *(const float4*)&s_b1w[ci * 8];
        float4 wb = *(const float4*)&s_b1w[ci * 8 + 4];
        a[0] += v * wa.x; a[1] += v * wa.y; a[2] += v * wa.z; a[3] += v * wa.w;
        a[4] += v * wb.x; a[5] += v * wb.y; a[6] += v * wb.z; a[7] += v * wb.w;
    }
    float g[8];
    #pragma unroll
    for (int j = 0; j < 8; ++j) g[j] = gelu_exact(a[j]);
    float basis[8];
    #pragma unroll
    for (int i = 0; i < 8; ++i) {
        float s = s_b2b[i];
        #pragma unroll
        for (int j = 0; j < 8; ++j) s += g[j] * s_b2w[i * 8 + j];
        basis[i] = s;
    }
    // softmax over 8
    {
        float m = basis[0];
        #pragma unroll
        for (int i = 1; i < 8; ++i) m = fmaxf(m, basis[i]);
        float s = 0.f;
        #pragma unroll
        for (int i = 0; i < 8; ++i) { basis[i] = expf(basis[i] - m); s += basis[i]; }
        float inv = 1.f / s;
        #pragma unroll
        for (int i = 0; i < 8; ++i) basis[i] *= inv;
    }

    // ---- MLP2 on flux (128 -> 6), with nan->0 ----
    float t[8];
    #pragma unroll
    for (int j = 0; j < 8; ++j) t[j] = s_t1b[j];
    const float* fp = flux + (size_t)b * EE * HW + yx;
    #pragma unroll 8
    for (int ci = 0; ci < EE; ++ci) {
        float v = fp[(size_t)ci * HW];
        v = (v == v) ? v : 0.f;
        float4 wa = *(const float4*)&s_t1w[ci * 8];
        float4 wb = *(const float4*)&s_t1w[ci * 8 + 4];
        t[0] += v * wa.x; t[1] += v * wa.y; t[2] += v * wa.z; t[3] += v * wa.w;
        t[4] += v * wb.x; t[5] += v * wb.y; t[6] += v * wb.z; t[7] += v * wb.w;
    }
    float gt[6];
    #pragma unroll
    for (int j = 0; j < NT; ++j) gt[j] = gelu_exact(t[j]);
    float task[6];
    #pragma unroll
    for (int i = 0; i < NT; ++i) {
        float s = s_t2b[i];
        #pragma unroll
        for (int j = 0; j < NT; ++j) s += gt[j] * s_t2w[i * 6 + j];
        task[i] = s;
    }
    // softmax over 6
    {
        float m = task[0];
        #pragma unroll
        for (int i = 1; i < NT; ++i) m = fmaxf(m, task[i]);
        float s = 0.f;
        #pragma unroll
        for (int i = 0; i < NT; ++i) { task[i] = expf(task[i] - m); s += task[i]; }
        float inv = 1.f / s;
        #pragma unroll
        for (int i = 0; i < NT; ++i) task[i] *= inv;
    }

    // ---- outer product -> c ----
    __hip_bfloat16* cp = c + (size_t)b * NC * HW + yx;
    #pragma unroll
    for (int tt = 0; tt < NT; ++tt) {
        #pragma unroll
        for (int k = 0; k < NB; ++k) {
            cp[(size_t)(tt * NB + k) * HW] = __float2bfloat16(task[tt] * basis[k]);
        }
    }
}

// ---------------- Kernel C: 3x3 conv, 48 -> 128 channels ----------------
// grid: 8192 = b(8) * y(256) * xstrip(4); block 256 = 4 waves
// wave w handles out channels [32w, 32w+32); lane = pixel x offset in strip
__global__ __launch_bounds__(256) void conv_kernel(
    const __hip_bfloat16* __restrict__ c,  // [8][48][256][256]
    const float* __restrict__ Wf,          // [48*9][128]
    float* __restrict__ out)               // [8][128][256][256]
{
    __shared__ float tile[NC][3][68];

    int bid = blockIdx.x;
    int sx = bid & 3;
    int y  = (bid >> 2) & 255;
    int b  = bid >> 10;
    int x0 = sx * 64;

    int tid = threadIdx.x;
    // stage c halo tile: 48 ch x 3 rows x 66 cols
    for (int idx = tid; idx < NC * 3 * 66; idx += 256) {
        int ci = idx / 198;
        int r  = idx - ci * 198;
        int dy = r / 66;
        int j  = r - dy * 66;
        int gy = y + dy - 1;
        int gx = x0 - 1 + j;
        float v = 0.f;
        if ((unsigned)gy < 256u && (unsigned)gx < 256u)
            v = __bfloat162float(c[(((size_t)b * NC + ci) << 16) + (gy << 8) + gx]);
        tile[ci][dy][j] = v;
    }
    __syncthreads();

    int lane  = tid & 63;
    int wave  = tid >> 6;
    int obase = wave * 32;

    float acc[32];
    #pragma unroll
    for (int i = 0; i < 32; ++i) acc[i] = 0.f;

    for (int ci = 0; ci < NC; ++ci) {
        #pragma unroll
        for (int dy = 0; dy < 3; ++dy) {
            #pragma unroll
            for (int dx = 0; dx < 3; ++dx) {
                float v = tile[ci][dy][lane + dx];
                const float4* wp = (const float4*)(Wf + ((size_t)(ci * 9 + dy * 3 + dx) << 7) + obase);
                #pragma unroll
                for (int q = 0; q < 8; ++q) {
                    float4 w = wp[q];
                    acc[q * 4 + 0] += v * w.x;
                    acc[q * 4 + 1] += v * w.y;
                    acc[q * 4 + 2] += v * w.z;
                    acc[q * 4 + 3] += v * w.w;
                }
            }
        }
    }

    int px = x0 + lane;
    float* op = out + (((size_t)b * 128 + obase) << 16) + (y << 8) + px;
    #pragma unroll
    for (int i = 0; i < 32; ++i)
        op[(size_t)i << 16] = acc[i];
}

extern "C" void kernel_launch(void* const* d_in, const int* in_sizes, int n_in,
                              void* d_out, int out_size, void* d_ws, size_t ws_size,
                              hipStream_t stream) {
    const float* x      = (const float*)d_in[0];
    const float* flux   = (const float*)d_in[1];
    const float* prompt = (const float*)d_in[2];
    const float* conv_w = (const float*)d_in[3];
    const float* b1w    = (const float*)d_in[4];
    const float* b1b    = (const float*)d_in[5];
    const float* b2w    = (const float*)d_in[6];
    const float* b2b    = (const float*)d_in[7];
    const float* t1w    = (const float*)d_in[8];
    const float* t1b    = (const float*)d_in[9];
    const float* t2w    = (const float*)d_in[10];
    const float* t2b    = (const float*)d_in[11];
    float* out = (float*)d_out;

    // workspace layout: c (bf16, 8*48*65536*2 = 50,331,648 B) then Wf (432*128*4 B)
    char* ws = (char*)d_ws;
    __hip_bfloat16* c = (__hip_bfloat16*)ws;
    float* Wf = (float*)(ws + (size_t)8 * NC * HW * 2);

    fold_weights_kernel<<<432, 128, 0, stream>>>(conv_w, prompt, Wf);
    routing_kernel<<<2048, 256, 0, stream>>>(x, flux, b1w, b1b, b2w, b2b,
                                             t1w, t1b, t2w, t2b, c);
    conv_kernel<<<8192, 256, 0, stream>>>(c, Wf, out);
}

// Round 3
// 323.656 us; speedup vs baseline: 9.9953x; 9.9953x over previous
//
#include <hip/hip_runtime.h>
#include <hip/hip_bf16.h>
#include <math.h>

#define HW   65536   // 256*256
#define NB   8
#define NT   6
#define NC   48      // nt*nb combined channels
#define DIM  64
#define EE   128
#define KSTEPS 18    // K = 9 taps * 64 padded ch = 576 = 18 * 32
#define COLS 130

typedef short bf16x8 __attribute__((ext_vector_type(8)));
typedef float f32x4  __attribute__((ext_vector_type(4)));

__device__ __forceinline__ float gelu_exact(float v) {
    return 0.5f * v * (1.0f + erff(v * 0.70710678118654752f));
}

// ---------------- Kernel A: fold prompt into conv weights, fragment-ordered bf16 ----
// WfB flat index = ((kstep*8 + ob)*64 + lane)*8 + j   (bf16)
// maps to A[o][k]: o = ob*16 + (lane&15); k = kstep*32 + (lane>>4)*8 + j
// k -> tap = k>>6 (dy=tap/3, dx=tap%3), tk = k&63 (zero for tk>=48)
__global__ __launch_bounds__(256) void fold_weights_kernel(
    const float* __restrict__ conv_w,   // [128][128][3][3]
    const float* __restrict__ prompt,   // [6][8][128]
    unsigned short* __restrict__ WfB)   // [18][8][64][8] bf16
{
    int f = blockIdx.x * 256 + threadIdx.x;   // 0 .. 73727
    int j    = f & 7;
    int lane = (f >> 3) & 63;
    int ob   = (f >> 9) & 7;
    int ks   = f >> 12;

    int o = ob * 16 + (lane & 15);
    int k = ks * 32 + ((lane >> 4) << 3) + j;
    int tap = k >> 6;
    int tk  = k & 63;

    float acc = 0.f;
    if (tk < NC) {
        int dy = tap / 3;
        int dx = tap - dy * 3;
        const float* pw = conv_w + ((size_t)o * EE) * 9 + dy * 3 + dx;
        const float* pp = prompt + (size_t)tk * EE;
        #pragma unroll 4
        for (int e = 0; e < EE; ++e)
            acc += pw[(size_t)e * 9] * pp[e];
    }
    __hip_bfloat16 h = __float2bfloat16(acc);
    WfB[f] = *(unsigned short*)&h;
}

// ---------------- Kernel B: per-pixel routing -> c[b][y][x][48] (bf16, ch-innermost) ----
__global__ __launch_bounds__(256) void routing_kernel(
    const float* __restrict__ x,      // [8][64][256][256]
    const float* __restrict__ flux,   // [8][128][256][256]
    const float* __restrict__ b1w, const float* __restrict__ b1b,
    const float* __restrict__ b2w, const float* __restrict__ b2b,
    const float* __restrict__ t1w, const float* __restrict__ t1b,
    const float* __restrict__ t2w, const float* __restrict__ t2b,
    unsigned short* __restrict__ c)   // [8*65536][48] bf16
{
    __shared__ float s_b1w[DIM * 8];   // [ci][j] transposed
    __shared__ float s_t1w[EE * 8];    // [ci][j] transposed, j<6 padded with 0
    __shared__ float s_b2w[64];
    __shared__ float s_t2w[36];
    __shared__ float s_b1b[8], s_b2b[8], s_t1b[8], s_t2b[8];

    int tid = threadIdx.x;
    for (int i = tid; i < DIM * 8; i += 256) {
        int ci = i >> 3, j = i & 7;
        s_b1w[i] = b1w[j * DIM + ci];
    }
    for (int i = tid; i < EE * 8; i += 256) {
        int ci = i >> 3, j = i & 7;
        s_t1w[i] = (j < NT) ? t1w[j * EE + ci] : 0.f;
    }
    if (tid < 64) s_b2w[tid] = b2w[tid];
    if (tid < 36) s_t2w[tid] = t2w[tid];
    if (tid < 8) {
        s_b1b[tid] = b1b[tid];
        s_b2b[tid] = b2b[tid];
        s_t1b[tid] = (tid < NT) ? t1b[tid] : 0.f;
        s_t2b[tid] = (tid < NT) ? t2b[tid] : 0.f;
    }
    __syncthreads();

    int pid = blockIdx.x * 256 + tid;     // 0 .. 524287
    int b  = pid >> 16;
    int yx = pid & (HW - 1);

    // ---- MLP1 on x (64 -> 8) ----
    float a[8];
    #pragma unroll
    for (int j = 0; j < 8; ++j) a[j] = s_b1b[j];
    const float* xp = x + (size_t)b * DIM * HW + yx;
    #pragma unroll 8
    for (int ci = 0; ci < DIM; ++ci) {
        float v = xp[(size_t)ci * HW];
        float4 wa = *(const float4*)&s_b1w[ci * 8];
        float4 wb = *(const float4*)&s_b1w[ci * 8 + 4];
        a[0] += v * wa.x; a[1] += v * wa.y; a[2] += v * wa.z; a[3] += v * wa.w;
        a[4] += v * wb.x; a[5] += v * wb.y; a[6] += v * wb.z; a[7] += v * wb.w;
    }
    float g[8];
    #pragma unroll
    for (int j = 0; j < 8; ++j) g[j] = gelu_exact(a[j]);
    float basis[8];
    #pragma unroll
    for (int i = 0; i < 8; ++i) {
        float s = s_b2b[i];
        #pragma unroll
        for (int j = 0; j < 8; ++j) s += g[j] * s_b2w[i * 8 + j];
        basis[i] = s;
    }
    {
        float m = basis[0];
        #pragma unroll
        for (int i = 1; i < 8; ++i) m = fmaxf(m, basis[i]);
        float s = 0.f;
        #pragma unroll
        for (int i = 0; i < 8; ++i) { basis[i] = expf(basis[i] - m); s += basis[i]; }
        float inv = 1.f / s;
        #pragma unroll
        for (int i = 0; i < 8; ++i) basis[i] *= inv;
    }

    // ---- MLP2 on flux (128 -> 6), with nan->0 ----
    float t[8];
    #pragma unroll
    for (int j = 0; j < 8; ++j) t[j] = s_t1b[j];
    const float* fp = flux + (size_t)b * EE * HW + yx;
    #pragma unroll 8
    for (int ci = 0; ci < EE; ++ci) {
        float v = fp[(size_t)ci * HW];
        v = (v == v) ? v : 0.f;
        float4 wa = *(const float4*)&s_t1w[ci * 8];
        float4 wb = *(const float4*)&s_t1w[ci * 8 + 4];
        t[0] += v * wa.x; t[1] += v * wa.y; t[2] += v * wa.z; t[3] += v * wa.w;
        t[4] += v * wb.x; t[5] += v * wb.y; t[6] += v * wb.z; t[7] += v * wb.w;
    }
    float gt[6];
    #pragma unroll
    for (int j = 0; j < NT; ++j) gt[j] = gelu_exact(t[j]);
    float task[6];
    #pragma unroll
    for (int i = 0; i < NT; ++i) {
        float s = s_t2b[i];
        #pragma unroll
        for (int j = 0; j < NT; ++j) s += gt[j] * s_t2w[i * 6 + j];
        task[i] = s;
    }
    {
        float m = task[0];
        #pragma unroll
        for (int i = 1; i < NT; ++i) m = fmaxf(m, task[i]);
        float s = 0.f;
        #pragma unroll
        for (int i = 0; i < NT; ++i) { task[i] = expf(task[i] - m); s += task[i]; }
        float inv = 1.f / s;
        #pragma unroll
        for (int i = 0; i < NT; ++i) task[i] *= inv;
    }

    // ---- outer product -> c[pixel][48], packed bf16 pairs ----
    unsigned int w[24];
    #pragma unroll
    for (int i = 0; i < 24; ++i) {
        int i0 = 2 * i, i1 = 2 * i + 1;
        float v0 = task[i0 >> 3] * basis[i0 & 7];
        float v1 = task[i1 >> 3] * basis[i1 & 7];
        __hip_bfloat16 h0 = __float2bfloat16(v0);
        __hip_bfloat16 h1 = __float2bfloat16(v1);
        w[i] = (unsigned)(*(unsigned short*)&h0) | ((unsigned)(*(unsigned short*)&h1) << 16);
    }
    uint4* cp = (uint4*)((char*)c + (size_t)pid * 96);
    cp[0] = make_uint4(w[0],  w[1],  w[2],  w[3]);
    cp[1] = make_uint4(w[4],  w[5],  w[6],  w[7]);
    cp[2] = make_uint4(w[8],  w[9],  w[10], w[11]);
    cp[3] = make_uint4(w[12], w[13], w[14], w[15]);
    cp[4] = make_uint4(w[16], w[17], w[18], w[19]);
    cp[5] = make_uint4(w[20], w[21], w[22], w[23]);
}

// ---------------- Kernel C: implicit-GEMM 3x3 conv via bf16 MFMA ----------------
// grid 4096 = b(8) * y(256) * xstrip(2); block 256 = 4 waves
// block tile: M=128 out-ch  x  N=128 pixels (one row strip)
// wave wv: M-half wm=wv&1 (o0=wm*64, 4 M-frags), N-half wn=wv>>1 (4 N-groups)
__global__ __launch_bounds__(256, 3) void conv_kernel(
    const unsigned short* __restrict__ c,   // [8*65536][48] bf16
    const unsigned short* __restrict__ WfB, // [18][8][64][8] bf16 fragment-ordered
    float* __restrict__ out)                // [8][128][256][256] f32
{
    __shared__ uint4 tile4[3120];   // [3][130][64ch] bf16, XOR-swizzled (49,920 B)

    int bid = blockIdx.x;
    int s = bid & 1;
    int y = (bid >> 1) & 255;
    int b = bid >> 9;
    int x0 = s << 7;
    int tid = threadIdx.x;

    // zero-fill (covers ch 48..63 padding and image borders)
    #pragma unroll 4
    for (int i = tid; i < 3120; i += 256)
        tile4[i] = make_uint4(0u, 0u, 0u, 0u);
    __syncthreads();

    // stage c halo tile: 3 rows x 130 cols x 48ch, in 16B chunks (6 per pixel)
    for (int idx = tid; idx < 2340; idx += 256) {
        int dy  = idx / 780;
        int rem = idx - dy * 780;
        int col = rem / 6;
        int ch  = rem - col * 6;
        int gy = y + dy - 1;
        int gx = x0 - 1 + col;
        if ((unsigned)gy < 256u && (unsigned)gx < 256u) {
            const uint4* src = (const uint4*)(c + ((((size_t)b << 16) + (gy << 8) + gx) * 48) + ch * 8);
            int lb = ((dy * COLS + col) << 7) + (ch << 4);
            lb ^= (col & 7) << 4;
            tile4[lb >> 4] = *src;
        }
    }
    __syncthreads();

    int lane = tid & 63;
    int wv = tid >> 6;
    int wm = wv & 1;
    int wn = wv >> 1;
    int o0 = wm << 6;
    int nbase = wn << 2;          // N-group base (of 16-pixel groups)
    int lrow = lane & 15;         // m (for A/D) and n (for B/D)
    int lk   = lane >> 4;         // k sub-block

    f32x4 acc[4][4];
    #pragma unroll
    for (int mi = 0; mi < 4; ++mi)
        #pragma unroll
        for (int ni = 0; ni < 4; ++ni)
            acc[mi][ni] = (f32x4){0.f, 0.f, 0.f, 0.f};

    const char* tbase = (const char*)tile4;

    #pragma unroll
    for (int ks = 0; ks < KSTEPS; ++ks) {
        bf16x8 a[4];
        #pragma unroll
        for (int mi = 0; mi < 4; ++mi)
            a[mi] = *(const bf16x8*)(WfB + ((size_t)((ks * 8) + wm * 4 + mi) * 64 + lane) * 8);

        int tap = ks >> 1;
        int dy = tap / 3;            // constant after unroll
        int dx = tap - dy * 3;
        int ch0 = ((ks & 1) << 5) + (lk << 3);

        #pragma unroll
        for (int ni = 0; ni < 4; ++ni) {
            int col = ((nbase + ni) << 4) + lrow + dx;
            int lb = ((dy * COLS + col) << 7) + (ch0 << 1);
            lb ^= (col & 7) << 4;
            bf16x8 bfr = *(const bf16x8*)(tbase + lb);
            #pragma unroll
            for (int mi = 0; mi < 4; ++mi)
                acc[mi][ni] = __builtin_amdgcn_mfma_f32_16x16x32_bf16(a[mi], bfr, acc[mi][ni], 0, 0, 0);
        }
    }

    // D layout: col = lane&15 (pixel), row = (lane>>4)*4 + r (out channel)
    int orow = lk << 2;
    #pragma unroll
    for (int mi = 0; mi < 4; ++mi) {
        #pragma unroll
        for (int ni = 0; ni < 4; ++ni) {
            int o = o0 + mi * 16 + orow;
            int xx = x0 + ((nbase + ni) << 4) + lrow;
            float* op = out + (((size_t)(b * 128 + o)) << 16) + (y << 8) + xx;
            #pragma unroll
            for (int r = 0; r < 4; ++r)
                op[(size_t)r << 16] = acc[mi][ni][r];
        }
    }
}

extern "C" void kernel_launch(void* const* d_in, const int* in_sizes, int n_in,
                              void* d_out, int out_size, void* d_ws, size_t ws_size,
                              hipStream_t stream) {
    const float* x      = (const float*)d_in[0];
    const float* flux   = (const float*)d_in[1];
    const float* prompt = (const float*)d_in[2];
    const float* conv_w = (const float*)d_in[3];
    const float* b1w    = (const float*)d_in[4];
    const float* b1b    = (const float*)d_in[5];
    const float* b2w    = (const float*)d_in[6];
    const float* b2b    = (const float*)d_in[7];
    const float* t1w    = (const float*)d_in[8];
    const float* t1b    = (const float*)d_in[9];
    const float* t2w    = (const float*)d_in[10];
    const float* t2b    = (const float*)d_in[11];
    float* out = (float*)d_out;

    // ws: c [8*65536][48] bf16 = 50,331,648 B ; WfB [18][8][64][8] bf16 = 147,456 B
    char* ws = (char*)d_ws;
    unsigned short* c   = (unsigned short*)ws;
    unsigned short* WfB = (unsigned short*)(ws + (size_t)8 * HW * NC * 2);

    fold_weights_kernel<<<288, 256, 0, stream>>>(conv_w, prompt, WfB);
    routing_kernel<<<2048, 256, 0, stream>>>(x, flux, b1w, b1b, b2w, b2b,
                                             t1w, t1b, t2w, t2b, c);
    conv_kernel<<<4096, 256, 0, stream>>>(c, WfB, out);
}

// Round 4
// 258.708 us; speedup vs baseline: 12.5046x; 1.2510x over previous
//
#include <hip/hip_runtime.h>
#include <hip/hip_bf16.h>
#include <math.h>

#define HW   65536   // 256*256
#define NB   8
#define NT   6
#define NC   48      // nt*nb combined channels
#define DIM  64
#define EE   128
#define KSTEPS 14    // K = 9 taps * 48 ch = 432, padded to 448 = 14 * 32
#define KVALID 432
#define COLS 130

typedef short bf16x8 __attribute__((ext_vector_type(8)));
typedef float f32x4  __attribute__((ext_vector_type(4)));

__device__ __forceinline__ float gelu_exact(float v) {
    return 0.5f * v * (1.0f + erff(v * 0.70710678118654752f));
}

// ---------------- Kernel A: fold prompt into conv weights, fragment-ordered bf16 ----
// WfB flat index = ((kstep*8 + ob)*64 + lane)*8 + j   (bf16)
// A[o][k]: o = ob*16 + (lane&15); k = kstep*32 + (lane>>4)*8 + j
// k -> tap = k/48 (dy=tap/3, dx=tap%3), tk = k%48 ; zero for k>=432
__global__ __launch_bounds__(256) void fold_weights_kernel(
    const float* __restrict__ conv_w,   // [128][128][3][3]
    const float* __restrict__ prompt,   // [6][8][128]
    unsigned short* __restrict__ WfB)   // [14][8][64][8] bf16
{
    int f = blockIdx.x * 256 + threadIdx.x;   // 0 .. 57343
    int j    = f & 7;
    int lane = (f >> 3) & 63;
    int ob   = (f >> 9) & 7;
    int ks   = f >> 12;

    int o = ob * 16 + (lane & 15);
    int k = ks * 32 + ((lane >> 4) << 3) + j;

    float acc = 0.f;
    if (k < KVALID) {
        int tap = k / 48;
        int tk  = k - tap * 48;
        int dy = tap / 3;
        int dx = tap - dy * 3;
        const float* pw = conv_w + ((size_t)o * EE) * 9 + dy * 3 + dx;
        const float* pp = prompt + (size_t)tk * EE;
        #pragma unroll 4
        for (int e = 0; e < EE; ++e)
            acc += pw[(size_t)e * 9] * pp[e];
    }
    __hip_bfloat16 h = __float2bfloat16(acc);
    WfB[f] = *(unsigned short*)&h;
}

// ---------------- Kernel B: per-pixel routing -> c[b][y][x][48] (bf16, ch-innermost) ----
// 4 pixels per thread, float4 channel loads (16B/lane)
__global__ __launch_bounds__(256) void routing_kernel(
    const float* __restrict__ x,      // [8][64][256][256]
    const float* __restrict__ flux,   // [8][128][256][256]
    const float* __restrict__ b1w, const float* __restrict__ b1b,
    const float* __restrict__ b2w, const float* __restrict__ b2b,
    const float* __restrict__ t1w, const float* __restrict__ t1b,
    const float* __restrict__ t2w, const float* __restrict__ t2b,
    unsigned short* __restrict__ c)   // [8*65536][48] bf16
{
    __shared__ float s_b1w[DIM * 8];   // [ci][j] transposed
    __shared__ float s_t1w[EE * 8];    // [ci][j] transposed, j<6 padded with 0
    __shared__ float s_b2w[64];
    __shared__ float s_t2w[36];
    __shared__ float s_b1b[8], s_b2b[8], s_t1b[8], s_t2b[8];

    int tid = threadIdx.x;
    for (int i = tid; i < DIM * 8; i += 256) {
        int ci = i >> 3, j = i & 7;
        s_b1w[i] = b1w[j * DIM + ci];
    }
    for (int i = tid; i < EE * 8; i += 256) {
        int ci = i >> 3, j = i & 7;
        s_t1w[i] = (j < NT) ? t1w[j * EE + ci] : 0.f;
    }
    if (tid < 64) s_b2w[tid] = b2w[tid];
    if (tid < 36) s_t2w[tid] = t2w[tid];
    if (tid < 8) {
        s_b1b[tid] = b1b[tid];
        s_b2b[tid] = b2b[tid];
        s_t1b[tid] = (tid < NT) ? t1b[tid] : 0.f;
        s_t2b[tid] = (tid < NT) ? t2b[tid] : 0.f;
    }
    __syncthreads();

    int tid4 = blockIdx.x * 256 + tid;     // 0 .. 131071 ; pixels 4*tid4 .. +3
    int b  = tid4 >> 14;
    int yx = (tid4 << 2) & (HW - 1);

    // ---- MLP2 on flux (128 -> 6), with nan->0, 4 pixels ----
    float t[4][6];
    #pragma unroll
    for (int p = 0; p < 4; ++p)
        #pragma unroll
        for (int j = 0; j < NT; ++j) t[p][j] = s_t1b[j];
    const float* fp = flux + (size_t)b * EE * HW + yx;
    #pragma unroll 8
    for (int ci = 0; ci < EE; ++ci) {
        float4 v4 = *(const float4*)(fp + (size_t)ci * HW);
        float vv[4] = {v4.x, v4.y, v4.z, v4.w};
        #pragma unroll
        for (int p = 0; p < 4; ++p) {
            float v = vv[p];
            v = (v == v) ? v : 0.f;
            #pragma unroll
            for (int j = 0; j < NT; ++j)
                t[p][j] += v * s_t1w[ci * 8 + j];
        }
    }
    float task[4][6];
    #pragma unroll
    for (int p = 0; p < 4; ++p) {
        float gt[6];
        #pragma unroll
        for (int j = 0; j < NT; ++j) gt[j] = gelu_exact(t[p][j]);
        #pragma unroll
        for (int i = 0; i < NT; ++i) {
            float s = s_t2b[i];
            #pragma unroll
            for (int j = 0; j < NT; ++j) s += gt[j] * s_t2w[i * 6 + j];
            task[p][i] = s;
        }
        float m = task[p][0];
        #pragma unroll
        for (int i = 1; i < NT; ++i) m = fmaxf(m, task[p][i]);
        float s = 0.f;
        #pragma unroll
        for (int i = 0; i < NT; ++i) { task[p][i] = expf(task[p][i] - m); s += task[p][i]; }
        float inv = 1.f / s;
        #pragma unroll
        for (int i = 0; i < NT; ++i) task[p][i] *= inv;
    }

    // ---- MLP1 on x (64 -> 8), 4 pixels ----
    float a[4][8];
    #pragma unroll
    for (int p = 0; p < 4; ++p)
        #pragma unroll
        for (int j = 0; j < 8; ++j) a[p][j] = s_b1b[j];
    const float* xp = x + (size_t)b * DIM * HW + yx;
    #pragma unroll 8
    for (int ci = 0; ci < DIM; ++ci) {
        float4 v4 = *(const float4*)(xp + (size_t)ci * HW);
        float vv[4] = {v4.x, v4.y, v4.z, v4.w};
        float4 wa = *(const float4*)&s_b1w[ci * 8];
        float4 wb = *(const float4*)&s_b1w[ci * 8 + 4];
        #pragma unroll
        for (int p = 0; p < 4; ++p) {
            float v = vv[p];
            a[p][0] += v * wa.x; a[p][1] += v * wa.y; a[p][2] += v * wa.z; a[p][3] += v * wa.w;
            a[p][4] += v * wb.x; a[p][5] += v * wb.y; a[p][6] += v * wb.z; a[p][7] += v * wb.w;
        }
    }

    // per-pixel: gelu -> fc2 -> softmax -> outer product -> store 96B
    #pragma unroll
    for (int p = 0; p < 4; ++p) {
        float g[8];
        #pragma unroll
        for (int j = 0; j < 8; ++j) g[j] = gelu_exact(a[p][j]);
        float basis[8];
        #pragma unroll
        for (int i = 0; i < 8; ++i) {
            float s = s_b2b[i];
            #pragma unroll
            for (int j = 0; j < 8; ++j) s += g[j] * s_b2w[i * 8 + j];
            basis[i] = s;
        }
        float m = basis[0];
        #pragma unroll
        for (int i = 1; i < 8; ++i) m = fmaxf(m, basis[i]);
        float s = 0.f;
        #pragma unroll
        for (int i = 0; i < 8; ++i) { basis[i] = expf(basis[i] - m); s += basis[i]; }
        float inv = 1.f / s;
        #pragma unroll
        for (int i = 0; i < 8; ++i) basis[i] *= inv;

        unsigned int w[24];
        #pragma unroll
        for (int i = 0; i < 24; ++i) {
            int i0 = 2 * i, i1 = 2 * i + 1;
            float v0 = task[p][i0 >> 3] * basis[i0 & 7];
            float v1 = task[p][i1 >> 3] * basis[i1 & 7];
            __hip_bfloat16 h0 = __float2bfloat16(v0);
            __hip_bfloat16 h1 = __float2bfloat16(v1);
            w[i] = (unsigned)(*(unsigned short*)&h0) | ((unsigned)(*(unsigned short*)&h1) << 16);
        }
        uint4* cp = (uint4*)((char*)c + (size_t)(4 * tid4 + p) * 96);
        cp[0] = make_uint4(w[0],  w[1],  w[2],  w[3]);
        cp[1] = make_uint4(w[4],  w[5],  w[6],  w[7]);
        cp[2] = make_uint4(w[8],  w[9],  w[10], w[11]);
        cp[3] = make_uint4(w[12], w[13], w[14], w[15]);
        cp[4] = make_uint4(w[16], w[17], w[18], w[19]);
        cp[5] = make_uint4(w[20], w[21], w[22], w[23]);
    }
}

// ---------------- Kernel C: implicit-GEMM 3x3 conv via bf16 MFMA, K=448 ----------------
// grid 4096 = b(8) * y(256) * xstrip(2); block 256 = 4 waves
// block tile: M=128 out-ch  x  N=128 pixels (one row strip)
__global__ __launch_bounds__(256, 3) void conv_kernel(
    const unsigned short* __restrict__ c,   // [8*65536][48] bf16
    const unsigned short* __restrict__ WfB, // [14][8][64][8] bf16 fragment-ordered
    float* __restrict__ out)                // [8][128][256][256] f32
{
    __shared__ uint4 tile4[3120];   // [3][130][64ch] bf16, XOR-swizzled (49,920 B)

    int bid = blockIdx.x;
    int s = bid & 1;
    int y = (bid >> 1) & 255;
    int b = bid >> 9;
    int x0 = s << 7;
    int tid = threadIdx.x;

    // zero-fill (covers ch 48..63 padding and image borders)
    #pragma unroll 4
    for (int i = tid; i < 3120; i += 256)
        tile4[i] = make_uint4(0u, 0u, 0u, 0u);
    __syncthreads();

    // stage c halo tile: 3 rows x 130 cols x 48ch, in 16B chunks (6 per pixel)
    for (int idx = tid; idx < 2340; idx += 256) {
        int dy  = idx / 780;
        int rem = idx - dy * 780;
        int col = rem / 6;
        int ch  = rem - col * 6;
        int gy = y + dy - 1;
        int gx = x0 - 1 + col;
        if ((unsigned)gy < 256u && (unsigned)gx < 256u) {
            const uint4* src = (const uint4*)(c + ((((size_t)b << 16) + (gy << 8) + gx) * 48) + ch * 8);
            int lb = ((dy * COLS + col) << 7) + (ch << 4);
            lb ^= (col & 7) << 4;
            tile4[lb >> 4] = *src;
        }
    }
    __syncthreads();

    int lane = tid & 63;
    int wv = tid >> 6;
    int wm = wv & 1;
    int wn = wv >> 1;
    int o0 = wm << 6;
    int nbase = wn << 2;          // N-group base (of 16-pixel groups)
    int lrow = lane & 15;         // m (for A/D) and n (for B/D)
    int lk   = lane >> 4;         // k sub-block

    f32x4 acc[4][4];
    #pragma unroll
    for (int mi = 0; mi < 4; ++mi)
        #pragma unroll
        for (int ni = 0; ni < 4; ++ni)
            acc[mi][ni] = (f32x4){0.f, 0.f, 0.f, 0.f};

    const char* tbase = (const char*)tile4;

    #pragma unroll
    for (int ks = 0; ks < KSTEPS; ++ks) {
        bf16x8 a[4];
        #pragma unroll
        for (int mi = 0; mi < 4; ++mi)
            a[mi] = *(const bf16x8*)(WfB + ((size_t)((ks * 8) + wm * 4 + mi) * 64 + lane) * 8);

        // k0 = ks*32 + lk*8 ; tap = k0/48 (clamped), ch = k0 - tap*48
        int k0 = ks * 32 + (lk << 3);
        int tap = k0 / 48;
        if (tap > 8) tap = 8;        // k>=432 pad: lands in zeroed ch48..63 region
        int ch = k0 - tap * 48;
        int dy = tap / 3;
        int dx = tap - dy * 3;

        #pragma unroll
        for (int ni = 0; ni < 4; ++ni) {
            int col = ((nbase + ni) << 4) + lrow + dx;
            int lb = ((dy * COLS + col) << 7) + (ch << 1);
            lb ^= (col & 7) << 4;
            bf16x8 bfr = *(const bf16x8*)(tbase + lb);
            #pragma unroll
            for (int mi = 0; mi < 4; ++mi)
                acc[mi][ni] = __builtin_amdgcn_mfma_f32_16x16x32_bf16(a[mi], bfr, acc[mi][ni], 0, 0, 0);
        }
    }

    // D layout: col = lane&15 (pixel), row = (lane>>4)*4 + r (out channel)
    int orow = lk << 2;
    #pragma unroll
    for (int mi = 0; mi < 4; ++mi) {
        #pragma unroll
        for (int ni = 0; ni < 4; ++ni) {
            int o = o0 + mi * 16 + orow;
            int xx = x0 + ((nbase + ni) << 4) + lrow;
            float* op = out + (((size_t)(b * 128 + o)) << 16) + (y << 8) + xx;
            #pragma unroll
            for (int r = 0; r < 4; ++r)
                op[(size_t)r << 16] = acc[mi][ni][r];
        }
    }
}

extern "C" void kernel_launch(void* const* d_in, const int* in_sizes, int n_in,
                              void* d_out, int out_size, void* d_ws, size_t ws_size,
                              hipStream_t stream) {
    const float* x      = (const float*)d_in[0];
    const float* flux   = (const float*)d_in[1];
    const float* prompt = (const float*)d_in[2];
    const float* conv_w = (const float*)d_in[3];
    const float* b1w    = (const float*)d_in[4];
    const float* b1b    = (const float*)d_in[5];
    const float* b2w    = (const float*)d_in[6];
    const float* b2b    = (const float*)d_in[7];
    const float* t1w    = (const float*)d_in[8];
    const float* t1b    = (const float*)d_in[9];
    const float* t2w    = (const float*)d_in[10];
    const float* t2b    = (const float*)d_in[11];
    float* out = (float*)d_out;

    // ws: c [8*65536][48] bf16 = 50,331,648 B ; WfB [14][8][64][8] bf16 = 114,688 B
    char* ws = (char*)d_ws;
    unsigned short* c   = (unsigned short*)ws;
    unsigned short* WfB = (unsigned short*)(ws + (size_t)8 * HW * NC * 2);

    fold_weights_kernel<<<224, 256, 0, stream>>>(conv_w, prompt, WfB);
    routing_kernel<<<512, 256, 0, stream>>>(x, flux, b1w, b1b, b2w, b2b,
                                            t1w, t1b, t2w, t2b, c);
    conv_kernel<<<4096, 256, 0, stream>>>(c, WfB, out);
}